// Round 5
// baseline (675.710 us; speedup 1.0000x reference)
//
#include <hip/hip_runtime.h>

#define U_N 100000
#define I_N 50000
#define N_NODES 150000
#define EMB_D 64
#define NNZ 4800000
#define ND (N_NODES * EMB_D)          /* 9,600,000 */
#define ND4 (ND / 4)
#define UD4 (U_N * EMB_D / 4)

#define RPB 1024                              /* rows per bucket */
#define NB ((N_NODES + RPB - 1) / RPB)        /* 147 buckets */
#define TILE 4096                             /* edges per partition tile */
#define NTILE ((NNZ + TILE - 1) / TILE)       /* 1172 */

__device__ __forceinline__ unsigned short f2bf(float f) {
    unsigned int u = __float_as_uint(f);
    unsigned int r = (u + 0x7FFFu + ((u >> 16) & 1u)) >> 16;
    return (unsigned short)r;
}
__device__ __forceinline__ float bf2f(unsigned short h) {
    return __uint_as_float((unsigned int)h << 16);
}

// emb0 = concat(u,i); hb0 = bf16(emb0)
__global__ void k_init(const float4* __restrict__ u, const float4* __restrict__ it,
                       float4* __restrict__ emb0, ushort4* __restrict__ hb0) {
    int i = blockIdx.x * blockDim.x + threadIdx.x;
    if (i >= ND4) return;
    float4 v = (i < UD4) ? u[i] : it[i - UD4];
    emb0[i] = v;
    ushort4 h;
    h.x = f2bf(v.x); h.y = f2bf(v.y); h.z = f2bf(v.z); h.w = f2bf(v.w);
    hb0[i] = h;
}

// ---------------- bucket histogram (LDS-staged) ----------------
__global__ void k_bucket_hist(const int* __restrict__ row, int* __restrict__ bhist) {
    __shared__ int lh[NB];
    int t = threadIdx.x;
    for (int i = t; i < NB; i += 256) lh[i] = 0;
    __syncthreads();
    int base = blockIdx.x * TILE;
    int cnt = min(TILE, NNZ - base);
    for (int i = t; i < cnt; i += 256)
        atomicAdd(&lh[row[base + i] >> 10], 1);
    __syncthreads();
    for (int i = t; i < NB; i += 256)
        if (lh[i]) atomicAdd(&bhist[i], lh[i]);
}

__global__ void k_bucket_scan(const int* __restrict__ bhist, int* __restrict__ bbase,
                              int* __restrict__ bcur) {
    if (threadIdx.x == 0 && blockIdx.x == 0) {
        int run = 0;
        for (int i = 0; i < NB; ++i) { bbase[i] = run; bcur[i] = run; run += bhist[i]; }
        bbase[NB] = run;
    }
}

// ---------------- phase A: LDS-staged partition into row-buckets ------------
// tmp[p] = { (row_local<<18)|col , val_bits } grouped (unordered) by bucket
__global__ void k_partition(const int* __restrict__ row, const int* __restrict__ col,
                            const float* __restrict__ vals, int* __restrict__ bcur,
                            int2* __restrict__ tmp) {
    __shared__ int2 stage[TILE];
    __shared__ unsigned char stageB[TILE];
    __shared__ int hist[NB];
    __shared__ int scn[NB];
    __shared__ int gbase[NB];
    __shared__ int sums[256];
    int t = threadIdx.x;
    for (int i = t; i < NB; i += 256) hist[i] = 0;
    __syncthreads();
    int base = blockIdx.x * TILE;
    int cnt = min(TILE, NNZ - base);

    int  myb[16];
    int  myslot[16];
    int2 myp[16];
#pragma unroll
    for (int j = 0; j < 16; ++j) {
        int i = t + j * 256;
        myb[j] = -1;
        if (i < cnt) {
            int e = base + i;
            int r = row[e];
            int b = r >> 10;
            myb[j] = b;
            myp[j] = make_int2(((r & (RPB - 1)) << 18) | col[e], __float_as_int(vals[e]));
            myslot[j] = atomicAdd(&hist[b], 1);
        }
    }
    __syncthreads();
    int v = (t < NB) ? hist[t] : 0;
    sums[t] = v;
    __syncthreads();
    for (int off = 1; off < 256; off <<= 1) {
        int add = (t >= off) ? sums[t - off] : 0;
        __syncthreads();
        sums[t] += add;
        __syncthreads();
    }
    if (t < NB) scn[t] = sums[t] - v;
    __syncthreads();
    if (t < NB && v > 0) gbase[t] = atomicAdd(&bcur[t], v);
    __syncthreads();
#pragma unroll
    for (int j = 0; j < 16; ++j) {
        if (myb[j] >= 0) {
            int pos = scn[myb[j]] + myslot[j];
            stage[pos] = myp[j];
            stageB[pos] = (unsigned char)myb[j];
        }
    }
    __syncthreads();
    for (int i = t; i < cnt; i += 256) {
        int b = stageB[i];
        tmp[gbase[b] + (i - scn[b])] = stage[i];
    }
}

// ---------------- phase B1: within-bucket counting sort by col>>10 ----------
__global__ void k_colbin(const int* __restrict__ bbase, const int2* __restrict__ tmp,
                         int2* __restrict__ tmp2) {
    __shared__ int lh[1024];
    __shared__ int lsc[1024];
    int b = blockIdx.x, t = threadIdx.x;           // 1024 threads
    int s0 = bbase[b], n = bbase[b + 1] - s0;
    lh[t] = 0;
    __syncthreads();
    for (int i = t; i < n; i += 1024)
        atomicAdd(&lh[((unsigned)(tmp[s0 + i].x & 0x3FFFF)) >> 10], 1);
    __syncthreads();
    int v = lh[t];
    lsc[t] = v;
    __syncthreads();
    for (int off = 1; off < 1024; off <<= 1) {
        int add = (t >= off) ? lsc[t - off] : 0;
        __syncthreads();
        lsc[t] += add;
        __syncthreads();
    }
    lh[t] = lsc[t] - v;                             // exclusive prefix = cursor
    __syncthreads();
    for (int i = t; i < n; i += 1024) {
        int2 p = tmp[s0 + i];
        int bin = ((unsigned)(p.x & 0x3FFFF)) >> 10;
        int pos = s0 + atomicAdd(&lh[bin], 1);
        tmp2[pos] = p;
    }
}

// ---------------- phase B2: within-bucket row sort (approx col-stable) ------
__global__ void k_bucket_csr(const int* __restrict__ bbase, const int2* __restrict__ tmp2,
                             int2* __restrict__ edges, int* __restrict__ rp) {
    __shared__ int lh[RPB];
    __shared__ int lsc[RPB];
    int b = blockIdx.x, t = threadIdx.x;           // 1024 threads
    int s0 = bbase[b], s1 = bbase[b + 1];
    int n = s1 - s0;
    lh[t] = 0;
    __syncthreads();
    for (int i = t; i < n; i += 1024)
        atomicAdd(&lh[(unsigned)tmp2[s0 + i].x >> 18], 1);
    __syncthreads();
    int v = lh[t];
    lsc[t] = v;
    __syncthreads();
    for (int off = 1; off < 1024; off <<= 1) {
        int add = (t >= off) ? lsc[t - off] : 0;
        __syncthreads();
        lsc[t] += add;
        __syncthreads();
    }
    int excl = lsc[t] - v;
    int r = b * RPB + t;
    if (r < N_NODES) rp[r] = s0 + excl;
    if (b == NB - 1 && t == 0) rp[N_NODES] = NNZ;
    __syncthreads();
    lh[t] = excl;                                   // per-row cursor
    __syncthreads();
    // reading col-binned order; same-row edges keep ~col order (±1024 window)
    for (int i = t; i < n; i += 1024) {
        int2 p = tmp2[s0 + i];
        int rl = (unsigned)p.x >> 18;
        int pos = s0 + atomicAdd(&lh[rl], 1);
        edges[pos] = make_int2(p.x & 0x3FFFF, p.y);
    }
}

// ---------------- pull SpMM, one wave per row, lane = dim, bf16 gather ------
__device__ __forceinline__ float row_dot(const int* __restrict__ rp,
                                         const int2* __restrict__ edges,
                                         const unsigned short* __restrict__ x,
                                         int wid, int lane) {
    int start = __builtin_amdgcn_readfirstlane(rp[wid]);
    int end   = __builtin_amdgcn_readfirstlane(rp[wid + 1]);
    float s0 = 0.f, s1 = 0.f, s2 = 0.f, s3 = 0.f;
    int e = start;
    for (; e + 8 <= end; e += 8) {
        int2 E[8];
#pragma unroll
        for (int j = 0; j < 8; ++j) E[j] = edges[e + j];
        float g[8];
#pragma unroll
        for (int j = 0; j < 8; ++j) g[j] = bf2f(x[(size_t)E[j].x * EMB_D + lane]);
        s0 += __int_as_float(E[0].y) * g[0];
        s1 += __int_as_float(E[1].y) * g[1];
        s2 += __int_as_float(E[2].y) * g[2];
        s3 += __int_as_float(E[3].y) * g[3];
        s0 += __int_as_float(E[4].y) * g[4];
        s1 += __int_as_float(E[5].y) * g[5];
        s2 += __int_as_float(E[6].y) * g[6];
        s3 += __int_as_float(E[7].y) * g[7];
    }
    for (; e < end; ++e) {
        int2 ev = edges[e];
        s0 += __int_as_float(ev.y) * bf2f(x[(size_t)ev.x * EMB_D + lane]);
    }
    return (s0 + s1) + (s2 + s3);
}

__global__ void k_spmm_mid(const int* __restrict__ rp, const int2* __restrict__ edges,
                           const unsigned short* __restrict__ x,
                           unsigned short* __restrict__ y) {
    int wid = blockIdx.x * (blockDim.x >> 6) + (threadIdx.x >> 6);
    if (wid >= N_NODES) return;
    int lane = threadIdx.x & 63;
    float s = row_dot(rp, edges, x, wid, lane);
    y[(size_t)wid * EMB_D + lane] = f2bf(s);
}

// layer 3: acc = (e0 + y1 + y2 + s) * 0.25, all prior layers read as bf16
__global__ void k_spmm_fin(const int* __restrict__ rp, const int2* __restrict__ edges,
                           const unsigned short* __restrict__ x,
                           const unsigned short* __restrict__ e0,
                           const unsigned short* __restrict__ y1,
                           float* __restrict__ acc) {
    int wid = blockIdx.x * (blockDim.x >> 6) + (threadIdx.x >> 6);
    if (wid >= N_NODES) return;
    int lane = threadIdx.x & 63;
    float s = row_dot(rp, edges, x, wid, lane);
    size_t o = (size_t)wid * EMB_D + lane;
    acc[o] = (bf2f(e0[o]) + bf2f(y1[o]) + bf2f(x[o]) + s) * 0.25f;
}

extern "C" void kernel_launch(void* const* d_in, const int* in_sizes, int n_in,
                              void* d_out, int out_size, void* d_ws, size_t ws_size,
                              hipStream_t stream) {
    const float* user_emb = (const float*)d_in[0];
    const float* item_emb = (const float*)d_in[1];
    const int*   row      = (const int*)d_in[2];
    const int*   col      = (const int*)d_in[3];
    const float* vals     = (const float*)d_in[4];

    float* emb0 = (float*)d_out;            // [ND] output 0
    float* acc  = (float*)d_out + ND;       // [ND] output 1

    // ws: [tmp int2[NNZ] | tmp2 int2[NNZ] | edges int2[NNZ] | ints]
    // aliases: hb0,hb1 <- tmp (dead after B1);  hb2 <- tmp2 (dead after B2)
    int2* tmp   = (int2*)d_ws;
    int2* tmp2  = tmp + NNZ;
    int2* edges = tmp2 + NNZ;
    int*  ibase = (int*)(edges + NNZ);
    int*  rp    = ibase;                     // [N_NODES+1]
    int*  bhist = ibase + N_NODES + 1;       // [NB]
    int*  bbase = bhist + NB;                // [NB+1]
    int*  bcur  = bbase + NB + 1;            // [NB]
    unsigned short* hb0 = (unsigned short*)tmp;    // [ND]
    unsigned short* hb1 = hb0 + ND;                // [ND]
    unsigned short* hb2 = (unsigned short*)tmp2;   // [ND]

    const int BLK = 256;
    const int grid_nd = (ND4 + BLK - 1) / BLK;
    const int grid_spmm = (N_NODES * 64 + BLK - 1) / BLK;  // 1 wave per row

    // --- CSR build: hist -> scan -> partition -> col-bin sort -> row sort ---
    hipMemsetAsync(bhist, 0, NB * sizeof(int), stream);
    k_bucket_hist<<<NTILE, BLK, 0, stream>>>(row, bhist);
    k_bucket_scan<<<1, 64, 0, stream>>>(bhist, bbase, bcur);
    k_partition<<<NTILE, BLK, 0, stream>>>(row, col, vals, bcur, tmp);
    k_colbin<<<NB, 1024, 0, stream>>>(bbase, tmp, tmp2);
    // tmp now dead -> safe to write hb0
    k_init<<<grid_nd, BLK, 0, stream>>>((const float4*)user_emb,
                                        (const float4*)item_emb,
                                        (float4*)emb0, (ushort4*)hb0);
    k_bucket_csr<<<NB, 1024, 0, stream>>>(bbase, tmp2, edges, rp);
    // tmp2 now dead -> hb2 usable

    // --- 3 propagation layers (col-sorted edge lists => L2-local gathers) ---
    k_spmm_mid<<<grid_spmm, BLK, 0, stream>>>(rp, edges, hb0, hb1);
    k_spmm_mid<<<grid_spmm, BLK, 0, stream>>>(rp, edges, hb1, hb2);
    k_spmm_fin<<<grid_spmm, BLK, 0, stream>>>(rp, edges, hb2, hb0, hb1, acc);
}